// Round 5
// baseline (803.373 us; speedup 1.0000x reference)
//
#include <hip/hip_runtime.h>
#include <hip/hip_bf16.h>

// Problem constants (from reference)
#define SCREEN_W 1280
#define SCREEN_H 720
#define TILE_L   16
#define NBW      80    // ceil(1280/16)
#define NBH      45    // ceil(720/16)
#define NUM_TILE 3600  // 80*45
#define N_POINTS 32768

#define TOTAL_ITEMS (NUM_TILE * (N_POINTS / 4))   // 29,491,200 uint4 outputs
#define QUARTER     (TOTAL_ITEMS / 4)             // 7,372,800

typedef int v4i __attribute__((ext_vector_type(4)));

// ---------------------------------------------------------------------------
// Kernel A (unchanged, verified absmax 0): per-point tile-index ranges packed
// into one u32: ximin | ximax<<8 | yimin<<16 | yimax<<24 (half-open ranges).
// ---------------------------------------------------------------------------
__global__ void aabb_kernel(const float* __restrict__ pos2d,
                            const float* __restrict__ radius,
                            unsigned int* __restrict__ pk) {
    int t = blockIdx.x * blockDim.x + threadIdx.x;   // thread handles 4 points
    int n = t * 4;
    if (n >= N_POINTS) return;

    const float4* p4 = (const float4*)(pos2d + 2 * n);
    float4 p01 = p4[0];   // x0 y0 x1 y1
    float4 p23 = p4[1];   // x2 y2 x3 y3
    float4 r   = *(const float4*)(radius + n);

    float xs[4] = {p01.x, p01.z, p23.x, p23.z};
    float ys[4] = {p01.y, p01.w, p23.y, p23.w};
    float rs[4] = {r.x, r.y, r.z, r.w};

    uint4 outp;
    unsigned int* op = &outp.x;
#pragma unroll
    for (int j = 0; j < 4; ++j) {
        float x = xs[j], y = ys[j], rr = rs[j];
        int xmin = (int)fminf(fmaxf(x - rr, 0.0f), (float)SCREEN_W);
        int ymin = (int)fminf(fmaxf(y - rr, 0.0f), (float)SCREEN_H);
        int xmax = (int)fminf(fmaxf(x + rr, 0.0f), (float)SCREEN_W);
        int ymax = (int)fminf(fmaxf(y + rr, 0.0f), (float)SCREEN_H);
        unsigned int ximin = (unsigned int)(xmin >> 4);          // <= 80
        unsigned int ximax = (unsigned int)((xmax + 15) >> 4);   // <= 80
        unsigned int yimin = (unsigned int)(ymin >> 4);          // <= 45
        unsigned int yimax = (unsigned int)((ymax + 15) >> 4);   // <= 45
        op[j] = ximin | (ximax << 8) | (yimin << 16) | (yimax << 24);
    }
    *(uint4*)(pk + n) = outp;
}

// common per-item compute: item g -> correct 16 B of output
__device__ __forceinline__ v4i item_res(const uint4* __restrict__ pk, int g) {
    unsigned int tile = (unsigned int)g >> 13;
    int t = g & 8191;
    unsigned int xi = tile / (unsigned int)NBH;       // magic-mul
    unsigned int yi = tile - xi * (unsigned int)NBH;

    uint4 p = pk[t];
    const unsigned int* pp = &p.x;
    v4i res;
#pragma unroll
    for (int j = 0; j < 4; ++j) {
        unsigned int w = pp[j];
        unsigned int ximin =  w        & 0xFFu;
        unsigned int ximax = (w >> 8)  & 0xFFu;
        unsigned int yimin = (w >> 16) & 0xFFu;
        unsigned int yimax =  w >> 24;
        res[j] = (xi >= ximin && xi < ximax && yi >= yimin && yi < yimax) ? 1 : 0;
    }
    return res;
}

// ---------------------------------------------------------------------------
// Kernel B1: the known-best R4 mask (115,200 x 256, one-shot plain store).
// Kept EXACTLY so the final output is correct no matter what B2/B3 do, and
// so dur decomposes as dur = 446.5 + dur(B2) + T(B3).
// ---------------------------------------------------------------------------
__global__ void __launch_bounds__(256)
mask_kernel(const uint4* __restrict__ pk, int* __restrict__ out) {
    int tile = blockIdx.y;
    int t = blockIdx.x * blockDim.x + threadIdx.x;
    int n = t * 4;

    unsigned int xi = (unsigned int)(tile / NBH);
    unsigned int yi = (unsigned int)(tile - (int)xi * NBH);

    uint4 p = pk[t];
    const unsigned int* pp = &p.x;

    v4i res;
#pragma unroll
    for (int j = 0; j < 4; ++j) {
        unsigned int w = pp[j];
        unsigned int ximin =  w        & 0xFFu;
        unsigned int ximax = (w >> 8)  & 0xFFu;
        unsigned int yimin = (w >> 16) & 0xFFu;
        unsigned int yimax =  w >> 24;
        res[j] = (xi >= ximin && xi < ximax && yi >= yimin && yi < yimax) ? 1 : 0;
    }

    *(v4i*)(out + (size_t)tile * N_POINTS + n) = res;
}

// ---------------------------------------------------------------------------
// Kernel B2 (MEASUREMENT): quad-pass rotated plain-store. Each thread writes
// items {g, g+T/4, g+T/2, g+3T/4} (mod T), each with its CORRECT value
// (idempotent overwrite of B1's output -> absmax stays 0). Rewrites of any
// given cache line come from blocks ~28,800 apart in dispatch order (~36 µs),
// so L2 (32 MB vs 472 MB buffer) has evicted -> every pass pays full HBM
// write traffic. Duration ~4x a single mask pass (> 300 µs fill) -> THIS
// dispatch tops the rocprof table and finally exposes FETCH_SIZE/WRITE_SIZE
// for our store path:
//   FETCH >~ 1.5 GB  -> RFO/write-allocate read pass confirmed
//   FETCH ~  0       -> no hidden reads; write-path inefficiency instead
// Pure HIP, no inline asm (R8's asm run died; removing that variable).
// ---------------------------------------------------------------------------
__global__ void __launch_bounds__(256)
mask_quad_kernel(const uint4* __restrict__ pk, int* __restrict__ out) {
    int g = blockIdx.x * 256 + (int)threadIdx.x;     // [0, TOTAL_ITEMS)
#pragma unroll
    for (int p = 0; p < 4; ++p) {
        v4i res = item_res(pk, g);
        *(v4i*)(out + (size_t)g * 4) = res;
        g += QUARTER;
        if (g >= TOTAL_ITEMS) g -= TOTAL_ITEMS;
    }
}

// ---------------------------------------------------------------------------
// Kernel B3 (EXPERIMENT, orthogonal): single pass, XCD-contiguous remap.
// Default RR maps bid%8 -> XCD; this bijection gives each XCD one contiguous
// 1/8 of the output (59 MB) so its L2 write-backs stay in one DRAM region
// instead of 8 XCDs interleaving 1 KB chunks over the same region.
// 115200 % 8 == 0 -> bijective. Idempotent overwrite, correct values.
// T(B3) = dur_total - 446.5 - dur(B2 row).
// ---------------------------------------------------------------------------
__global__ void __launch_bounds__(256)
mask_xcd_kernel(const uint4* __restrict__ pk, int* __restrict__ out) {
    unsigned int bid = blockIdx.x;                               // [0,115200)
    unsigned int nb  = (bid & 7u) * (115200u / 8u) + (bid >> 3); // contiguous per XCD
    int g = (int)(nb * 256u + threadIdx.x);
    v4i res = item_res(pk, g);
    *(v4i*)(out + (size_t)g * 4) = res;
}

extern "C" void kernel_launch(void* const* d_in, const int* in_sizes, int n_in,
                              void* d_out, int out_size, void* d_ws, size_t ws_size,
                              hipStream_t stream) {
    const float* pos2d  = (const float*)d_in[0];
    const float* radius = (const float*)d_in[1];
    int* out = (int*)d_out;
    unsigned int* pk = (unsigned int*)d_ws;   // 32768 * 4 B = 128 KB

    // Kernel A: 32768 points / 4 per thread = 8192 threads
    aabb_kernel<<<dim3(8192 / 256), dim3(256), 0, stream>>>(pos2d, radius, pk);

    // B1: known-best baseline (exact 446.5 µs configuration)
    mask_kernel<<<dim3(32, NUM_TILE), dim3(256), 0, stream>>>((const uint4*)pk, out);

    // B2: quad-pass measurement dispatch (tops the counter table)
    mask_quad_kernel<<<dim3(TOTAL_ITEMS / 256), dim3(256), 0, stream>>>((const uint4*)pk, out);

    // B3: XCD-contiguous single-pass experiment
    mask_xcd_kernel<<<dim3(TOTAL_ITEMS / 256), dim3(256), 0, stream>>>((const uint4*)pk, out);
}

// Round 6
// 448.751 us; speedup vs baseline: 1.7902x; 1.7902x over previous
//
#include <hip/hip_runtime.h>
#include <hip/hip_bf16.h>

// Problem constants (from reference)
#define SCREEN_W 1280
#define SCREEN_H 720
#define TILE_L   16
#define NBW      80    // ceil(1280/16)
#define NBH      45    // ceil(720/16)
#define NUM_TILE 3600  // 80*45
#define N_POINTS 32768

#define TOTAL_ITEMS (NUM_TILE * (N_POINTS / 4))   // 29,491,200 uint4 outputs
#define QUARTER     (TOTAL_ITEMS / 4)             // 7,372,800 = 900 * 8192

typedef int v4i __attribute__((ext_vector_type(4)));

// ---------------------------------------------------------------------------
// Kernel A (unchanged, verified absmax 0): per-point tile-index ranges packed
// into one u32: ximin | ximax<<8 | yimin<<16 | yimax<<24 (half-open ranges).
// overlap_x(tile xi) <=> (xmin>>4) <= xi < ((xmax+15)>>4)
// ---------------------------------------------------------------------------
__global__ void aabb_kernel(const float* __restrict__ pos2d,
                            const float* __restrict__ radius,
                            unsigned int* __restrict__ pk) {
    int t = blockIdx.x * blockDim.x + threadIdx.x;   // thread handles 4 points
    int n = t * 4;
    if (n >= N_POINTS) return;

    const float4* p4 = (const float4*)(pos2d + 2 * n);
    float4 p01 = p4[0];   // x0 y0 x1 y1
    float4 p23 = p4[1];   // x2 y2 x3 y3
    float4 r   = *(const float4*)(radius + n);

    float xs[4] = {p01.x, p01.z, p23.x, p23.z};
    float ys[4] = {p01.y, p01.w, p23.y, p23.w};
    float rs[4] = {r.x, r.y, r.z, r.w};

    uint4 outp;
    unsigned int* op = &outp.x;
#pragma unroll
    for (int j = 0; j < 4; ++j) {
        float x = xs[j], y = ys[j], rr = rs[j];
        int xmin = (int)fminf(fmaxf(x - rr, 0.0f), (float)SCREEN_W);
        int ymin = (int)fminf(fmaxf(y - rr, 0.0f), (float)SCREEN_H);
        int xmax = (int)fminf(fmaxf(x + rr, 0.0f), (float)SCREEN_W);
        int ymax = (int)fminf(fmaxf(y + rr, 0.0f), (float)SCREEN_H);
        unsigned int ximin = (unsigned int)(xmin >> 4);          // <= 80
        unsigned int ximax = (unsigned int)((xmax + 15) >> 4);   // <= 80
        unsigned int yimin = (unsigned int)(ymin >> 4);          // <= 45
        unsigned int yimax = (unsigned int)((ymax + 15) >> 4);   // <= 45
        op[j] = ximin | (ximax << 8) | (yimin << 16) | (yimax << 24);
    }
    *(uint4*)(pk + n) = outp;
}

// ---------------------------------------------------------------------------
// Kernel B (R10): single-pass "rotated quad" — the structure rocprof PROVED
// runs at 6.0 TB/s with FETCH~0 (R9 mask_quad_kernel: 1.888 GB / 314 µs,
// FETCH_SIZE 166 KB -> no RFO; the lever is 4 INDEPENDENT 16 B stores in
// flight per thread amortizing the pk-load + end-of-kernel store-drain
// latency that capped one-store-per-thread shapes at ~3.3 TB/s).
//
// Thread g in [0, QUARTER) writes items {g, g+Q, g+2Q, g+3Q} — one full
// pass, each item exactly once. QUARTER = 900*8192, so t = g&8191 is
// INVARIANT across the 4 stores: one uint4 pk load (L2-resident 128 KB
// table), tile steps by +900 per store.
// Grid: QUARTER/256 = 28,800 blocks x 256 threads.
// ---------------------------------------------------------------------------
__global__ void __launch_bounds__(256)
mask_kernel(const uint4* __restrict__ pk, int* __restrict__ out) {
    const int g = blockIdx.x * 256 + (int)threadIdx.x;   // [0, QUARTER)
    const int t = g & 8191;                              // invariant point-group
    const unsigned int tile0 = (unsigned int)g >> 13;    // [0, 900)

    uint4 p = pk[t];
    const unsigned int* pp = &p.x;

#pragma unroll
    for (int k = 0; k < 4; ++k) {
        const unsigned int tile = tile0 + 900u * (unsigned int)k;
        const unsigned int xi = tile / (unsigned int)NBH;   // magic-mul
        const unsigned int yi = tile - xi * (unsigned int)NBH;

        v4i res;
#pragma unroll
        for (int j = 0; j < 4; ++j) {
            unsigned int w = pp[j];
            unsigned int ximin =  w        & 0xFFu;
            unsigned int ximax = (w >> 8)  & 0xFFu;
            unsigned int yimin = (w >> 16) & 0xFFu;
            unsigned int yimax =  w >> 24;
            res[j] = (xi >= ximin && xi < ximax && yi >= yimin && yi < yimax) ? 1 : 0;
        }

        // 4 independent plain coalesced stores, addresses QUARTER*16 B apart;
        // all issued before the single end-of-kernel vmcnt drain.
        *(v4i*)(out + (size_t)(g + k * QUARTER) * 4) = res;
    }
}

extern "C" void kernel_launch(void* const* d_in, const int* in_sizes, int n_in,
                              void* d_out, int out_size, void* d_ws, size_t ws_size,
                              hipStream_t stream) {
    const float* pos2d  = (const float*)d_in[0];
    const float* radius = (const float*)d_in[1];
    int* out = (int*)d_out;
    unsigned int* pk = (unsigned int*)d_ws;   // 32768 * 4 B = 128 KB

    // Kernel A: 32768 points / 4 per thread = 8192 threads
    aabb_kernel<<<dim3(8192 / 256), dim3(256), 0, stream>>>(pos2d, radius, pk);

    // Kernel B: 28,800 blocks x 256 threads, 4 rotated stores per thread
    mask_kernel<<<dim3(QUARTER / 256), dim3(256), 0, stream>>>((const uint4*)pk, out);
}